// Round 2
// baseline (413.840 us; speedup 1.0000x reference)
//
#include <hip/hip_runtime.h>

#define BATCH 32
#define NODES 20000
#define FEAT  64
#define OUT   64
#define EIG   16

// ---- stage1 geometry: 32 chunks x 640 nodes (32*640 = 20480 >= 20000) ----
#define CH1     32     // chunks (= gridDim.x); grid 32x32 = 1024 blocks = 4/CU, one round
#define S1_NPB  640    // nodes per block
#define S1_NPW  160    // nodes per wave (4 waves/block)

__global__ void k_zero(float* __restrict__ p, int n) {
    int idx = blockIdx.x * blockDim.x + threadIdx.x;
    if (idx < n) p[idx] = 0.0f;
}

// z[b,i,f] = sum_m V[m,f] * x[b,m,i]
// Lane (ig = lane&15, fg = lane>>4) owns z[4ig..4ig+3, 4fg..4fg+3]: acc = 16 VGPRs.
// Per node: one float4 x load (wave: one 256 B x-row, 4x lane-dup dedups in TA/L1),
// one float4 V broadcast load (64 B eff, L1-resident). 16 FMAs. No per-node LDS/shfl.
// Cross-wave combine once per block via LDS, then 4 scalar atomicAdds per thread
// (32 contenders per z address — baseline had 79 and was fine).
__global__ __launch_bounds__(256, 4)
void k_stage1(const float* __restrict__ x, const float* __restrict__ V,
              float* __restrict__ z) {
    const int c = blockIdx.x;
    const int b = blockIdx.y;
    const int t = threadIdx.x;
    const int lane = t & 63;
    const int wv   = t >> 6;
    const int ig   = lane & 15;
    const int fg   = lane >> 4;

    float4 a0 = make_float4(0.f,0.f,0.f,0.f), a1 = a0, a2 = a0, a3 = a0;

    const int wb = c * S1_NPB + wv * S1_NPW;
    int cnt = NODES - wb;
    if (cnt > S1_NPW) cnt = S1_NPW;

    const float* xp = x + ((size_t)b * NODES + wb) * FEAT + ig * 4;
    const float* vp = V + (size_t)wb * EIG + fg * 4;

#pragma unroll 8
    for (int m = 0; m < cnt; m++) {
        const float4 xv = *(const float4*)(xp + (size_t)m * FEAT);
        const float4 vv = *(const float4*)(vp + (size_t)m * EIG);
        a0.x += vv.x * xv.x; a0.y += vv.y * xv.x; a0.z += vv.z * xv.x; a0.w += vv.w * xv.x;
        a1.x += vv.x * xv.y; a1.y += vv.y * xv.y; a1.z += vv.z * xv.y; a1.w += vv.w * xv.y;
        a2.x += vv.x * xv.z; a2.y += vv.y * xv.z; a2.z += vv.z * xv.z; a2.w += vv.w * xv.z;
        a3.x += vv.x * xv.w; a3.y += vv.y * xv.w; a3.z += vv.z * xv.w; a3.w += vv.w * xv.w;
    }

    // combine 4 waves in LDS -> thread t owns (source-lane ls, quad q)
    __shared__ float4 red[4][256];   // [q][wv*64+lane], 16 KiB
    red[0][t] = a0; red[1][t] = a1; red[2][t] = a2; red[3][t] = a3;
    __syncthreads();

    const int ls = t >> 2;   // source lane 0..63
    const int q  = t & 3;    // which i within the lane's i-quad
    float4 s  = red[q][ls];
    const float4 sb = red[q][ 64 + ls];
    const float4 sc = red[q][128 + ls];
    const float4 sd = red[q][192 + ls];
    s.x += sb.x + sc.x + sd.x;
    s.y += sb.y + sc.y + sd.y;
    s.z += sb.z + sc.z + sd.z;
    s.w += sb.w + sc.w + sd.w;

    // z element: i = 4*(ls&15)+q, f = 4*(ls>>4) + r  (r = vector component)
    float* zp = z + (size_t)b * (FEAT * EIG)
                  + (size_t)(4 * (ls & 15) + q) * EIG + 4 * (ls >> 4);
    atomicAdd(zp + 0, s.x);
    atomicAdd(zp + 1, s.y);
    atomicAdd(zp + 2, s.z);
    atomicAdd(zp + 3, s.w);
}

// w[b,j,e] = sum_{i,f} G[j,i,e,f] * z[b,i,f]   (tiny: 2048 single-wave blocks)
__global__ void k_stage2(const float* __restrict__ G, const float* __restrict__ z,
                         float* __restrict__ w) {
    const int j = blockIdx.x;
    const int b = blockIdx.y;
    const int t = threadIdx.x;

    __shared__ float zs[FEAT * EIG];
    {
        const float4* zsrc = (const float4*)(z + (size_t)b * FEAT * EIG);
        float4* zdst = (float4*)zs;
#pragma unroll
        for (int k = t; k < FEAT * EIG / 4; k += 64) zdst[k] = zsrc[k];
    }
    __syncthreads();

    const int e = t & 15;
    const int s = t >> 4;
    float acc = 0.0f;
    const float* Gj = G + (size_t)j * FEAT * EIG * EIG;

    for (int i = s * 16; i < s * 16 + 16; i++) {
        const float4* gp = (const float4*)(Gj + ((size_t)i * EIG + e) * EIG);
        const float4* zp = (const float4*)(zs + i * EIG);
        const float4 g0 = gp[0], g1 = gp[1], g2 = gp[2], g3 = gp[3];
        const float4 z0 = zp[0], z1 = zp[1], z2 = zp[2], z3 = zp[3];
        acc += g0.x * z0.x + g0.y * z0.y + g0.z * z0.z + g0.w * z0.w
             + g1.x * z1.x + g1.y * z1.y + g1.z * z1.z + g1.w * z1.w
             + g2.x * z2.x + g2.y * z2.y + g2.z * z2.z + g2.w * z2.w
             + g3.x * z3.x + g3.y * z3.y + g3.z * z3.z + g3.w * z3.w;
    }

    __shared__ float red[64];
    red[t] = acc;
    __syncthreads();
    if (s == 0)
        w[((size_t)b * OUT + j) * EIG + e] = red[e] + red[16 + e] + red[32 + e] + red[48 + e];
}

// out[b,n,j] = sum_e V[n,e] * w[b,j,e]
// Thread owns 4 j's (w[4][4] float4 in regs) -> float4 stores (1 KiB/wave-inst).
// V rows via broadcast global loads (L1-resident). No LDS, no barriers.
#define DOT16(u) (v0.x*W[u][0].x + v0.y*W[u][0].y + v0.z*W[u][0].z + v0.w*W[u][0].w \
                + v1.x*W[u][1].x + v1.y*W[u][1].y + v1.z*W[u][1].z + v1.w*W[u][1].w \
                + v2.x*W[u][2].x + v2.y*W[u][2].y + v2.z*W[u][2].z + v2.w*W[u][2].w \
                + v3.x*W[u][3].x + v3.y*W[u][3].y + v3.z*W[u][3].z + v3.w*W[u][3].w)

__global__ __launch_bounds__(256, 4)
void k_stage3(const float* __restrict__ V, const float* __restrict__ w,
              float* __restrict__ out) {
    const int c = blockIdx.x;        // 0..31, 640 nodes each
    const int b = blockIdx.y;
    const int t = threadIdx.x;
    const int jg = t & 15;           // j = 4*jg + u
    const int ns = t >> 4;           // node sub 0..15

    const float* wp = w + ((size_t)b * OUT + 4 * jg) * EIG;
    float4 W[4][4];
#pragma unroll
    for (int u = 0; u < 4; u++)
#pragma unroll
        for (int vr = 0; vr < 4; vr++)
            W[u][vr] = *(const float4*)(wp + u * EIG + vr * 4);

    const int nb = c * 640 + ns;
    float* ob = out + (size_t)b * NODES * OUT + 4 * jg;

#pragma unroll 2
    for (int it = 0; it < 40; it++) {
        const int n = nb + it * 16;
        if (n < NODES) {
            const float* vp = V + (size_t)n * EIG;
            const float4 v0 = *(const float4*)(vp);
            const float4 v1 = *(const float4*)(vp + 4);
            const float4 v2 = *(const float4*)(vp + 8);
            const float4 v3 = *(const float4*)(vp + 12);
            float4 o;
            o.x = DOT16(0);
            o.y = DOT16(1);
            o.z = DOT16(2);
            o.w = DOT16(3);
            *(float4*)(ob + (size_t)n * OUT) = o;
        }
    }
}

extern "C" void kernel_launch(void* const* d_in, const int* in_sizes, int n_in,
                              void* d_out, int out_size, void* d_ws, size_t ws_size,
                              hipStream_t stream) {
    const float* x = (const float*)d_in[0];   // [32, 20000, 64]
    const float* V = (const float*)d_in[1];   // [20000, 16]
    const float* G = (const float*)d_in[2];   // [64, 64, 16, 16]
    float* out = (float*)d_out;               // [32, 20000, 64]

    float* z = (float*)d_ws;                          // [32, 64, 16]
    float* w = z + (size_t)BATCH * FEAT * EIG;        // [32, 64, 16]

    const int zn = BATCH * FEAT * EIG;  // 32768
    k_zero<<<(zn + 255) / 256, 256, 0, stream>>>(z, zn);

    k_stage1<<<dim3(CH1, BATCH), 256, 0, stream>>>(x, V, z);
    k_stage2<<<dim3(OUT, BATCH), 64, 0, stream>>>(G, z, w);
    k_stage3<<<dim3(CH1, BATCH), 256, 0, stream>>>(V, w, out);
}

// Round 4
// 353.447 us; speedup vs baseline: 1.1709x; 1.1709x over previous
//
#include <hip/hip_runtime.h>

#define BATCH 32
#define NODES 20000
#define FEAT  64
#define OUT   64
#define EIG   16

// ---- stage1: 32 chunks x 640 nodes; wave handles 160 nodes, 4/iteration ----
#define CH1     32
#define S1_NPB  640
#define S1_NPW  160

__global__ void k_zero(float* __restrict__ p, int n) {
    int idx = blockIdx.x * blockDim.x + threadIdx.x;
    if (idx < n) p[idx] = 0.0f;
}

// z[b,i,f] = sum_m V[m,f] * x[b,m,i]
// Lane (ms = lane>>4, ig = lane&15): per iteration processes node n = m0+ms,
// loading x[n, 4ig..4ig+3] -> wave-inst covers 4 consecutive 256 B rows = 1 KiB
// fully coalesced. V row (64 B) via 4 broadcast float4 loads (L1-resident).
// acc[ii][q] = z[4ig+ii][4q..4q+3] partial: 64 VGPRs. 64 FMA/lane/node.
// Tail: shfl_xor over ms groups, padded-LDS cross-wave combine, 1024 atomics.
__global__ __launch_bounds__(256)
void k_stage1(const float* __restrict__ x, const float* __restrict__ V,
              float* __restrict__ z) {
    const int c = blockIdx.x;
    const int b = blockIdx.y;
    const int t = threadIdx.x;
    const int lane = t & 63;
    const int wv   = t >> 6;
    const int ms   = lane >> 4;   // node-sub 0..3
    const int ig   = lane & 15;   // i-quad

    float4 acc[4][4];
#pragma unroll
    for (int ii = 0; ii < 4; ii++)
#pragma unroll
        for (int q = 0; q < 4; q++) acc[ii][q] = make_float4(0.f,0.f,0.f,0.f);

    const int wb = c * S1_NPB + wv * S1_NPW;   // multiple of 160; NODES = 125*160
    if (wb < NODES) {                          // full 160 nodes when active
        const float* xp = x + ((size_t)b * NODES + wb + ms) * FEAT + ig * 4;
        const float* vp = V + (size_t)(wb + ms) * EIG;

#pragma unroll 2
        for (int mm = 0; mm < S1_NPW / 4; mm++) {
            const float4 xv = *(const float4*)(xp + (size_t)mm * 4 * FEAT);
            const float4 v0 = *(const float4*)(vp + (size_t)mm * 4 * EIG);
            const float4 v1 = *(const float4*)(vp + (size_t)mm * 4 * EIG + 4);
            const float4 v2 = *(const float4*)(vp + (size_t)mm * 4 * EIG + 8);
            const float4 v3 = *(const float4*)(vp + (size_t)mm * 4 * EIG + 12);
            acc[0][0].x += xv.x*v0.x; acc[0][0].y += xv.x*v0.y; acc[0][0].z += xv.x*v0.z; acc[0][0].w += xv.x*v0.w;
            acc[0][1].x += xv.x*v1.x; acc[0][1].y += xv.x*v1.y; acc[0][1].z += xv.x*v1.z; acc[0][1].w += xv.x*v1.w;
            acc[0][2].x += xv.x*v2.x; acc[0][2].y += xv.x*v2.y; acc[0][2].z += xv.x*v2.z; acc[0][2].w += xv.x*v2.w;
            acc[0][3].x += xv.x*v3.x; acc[0][3].y += xv.x*v3.y; acc[0][3].z += xv.x*v3.z; acc[0][3].w += xv.x*v3.w;
            acc[1][0].x += xv.y*v0.x; acc[1][0].y += xv.y*v0.y; acc[1][0].z += xv.y*v0.z; acc[1][0].w += xv.y*v0.w;
            acc[1][1].x += xv.y*v1.x; acc[1][1].y += xv.y*v1.y; acc[1][1].z += xv.y*v1.z; acc[1][1].w += xv.y*v1.w;
            acc[1][2].x += xv.y*v2.x; acc[1][2].y += xv.y*v2.y; acc[1][2].z += xv.y*v2.z; acc[1][2].w += xv.y*v2.w;
            acc[1][3].x += xv.y*v3.x; acc[1][3].y += xv.y*v3.y; acc[1][3].z += xv.y*v3.z; acc[1][3].w += xv.y*v3.w;
            acc[2][0].x += xv.z*v0.x; acc[2][0].y += xv.z*v0.y; acc[2][0].z += xv.z*v0.z; acc[2][0].w += xv.z*v0.w;
            acc[2][1].x += xv.z*v1.x; acc[2][1].y += xv.z*v1.y; acc[2][1].z += xv.z*v1.z; acc[2][1].w += xv.z*v1.w;
            acc[2][2].x += xv.z*v2.x; acc[2][2].y += xv.z*v2.y; acc[2][2].z += xv.z*v2.z; acc[2][2].w += xv.z*v2.w;
            acc[2][3].x += xv.z*v3.x; acc[2][3].y += xv.z*v3.y; acc[2][3].z += xv.z*v3.z; acc[2][3].w += xv.z*v3.w;
            acc[3][0].x += xv.w*v0.x; acc[3][0].y += xv.w*v0.y; acc[3][0].z += xv.w*v0.z; acc[3][0].w += xv.w*v0.w;
            acc[3][1].x += xv.w*v1.x; acc[3][1].y += xv.w*v1.y; acc[3][1].z += xv.w*v1.z; acc[3][1].w += xv.w*v1.w;
            acc[3][2].x += xv.w*v2.x; acc[3][2].y += xv.w*v2.y; acc[3][2].z += xv.w*v2.z; acc[3][2].w += xv.w*v2.w;
            acc[3][3].x += xv.w*v3.x; acc[3][3].y += xv.w*v3.y; acc[3][3].z += xv.w*v3.z; acc[3][3].w += xv.w*v3.w;
        }
    }

    // reduce over ms groups (lanes l, l^16, l^32, l^48)
#pragma unroll
    for (int ii = 0; ii < 4; ii++)
#pragma unroll
        for (int q = 0; q < 4; q++) {
            acc[ii][q].x += __shfl_xor(acc[ii][q].x, 16); acc[ii][q].x += __shfl_xor(acc[ii][q].x, 32);
            acc[ii][q].y += __shfl_xor(acc[ii][q].y, 16); acc[ii][q].y += __shfl_xor(acc[ii][q].y, 32);
            acc[ii][q].z += __shfl_xor(acc[ii][q].z, 16); acc[ii][q].z += __shfl_xor(acc[ii][q].z, 32);
            acc[ii][q].w += __shfl_xor(acc[ii][q].w, 16); acc[ii][q].w += __shfl_xor(acc[ii][q].w, 32);
        }

    __shared__ float4 zred[4][16][17];   // pad 17: breaks bank alignment; 17.4 KiB
    if (ms == 0) {
#pragma unroll
        for (int ii = 0; ii < 4; ii++)
#pragma unroll
            for (int q = 0; q < 4; q++) zred[wv][ig][ii * 4 + q] = acc[ii][q];
    }
    __syncthreads();

    // thread t owns z float4-chunk t: i = t>>2, q = t&3
    const int i = t >> 2, q = t & 3;
    const float4 s0 = zred[0][i >> 2][(i & 3) * 4 + q];
    const float4 s1 = zred[1][i >> 2][(i & 3) * 4 + q];
    const float4 s2 = zred[2][i >> 2][(i & 3) * 4 + q];
    const float4 s3 = zred[3][i >> 2][(i & 3) * 4 + q];
    float* zp = z + (size_t)b * (FEAT * EIG) + (size_t)i * EIG + q * 4;
    atomicAdd(zp + 0, s0.x + s1.x + s2.x + s3.x);
    atomicAdd(zp + 1, s0.y + s1.y + s2.y + s3.y);
    atomicAdd(zp + 2, s0.z + s1.z + s2.z + s3.z);
    atomicAdd(zp + 3, s0.w + s1.w + s2.w + s3.w);
}

// w[b,j,e] = sum_{i,f} G[j,i,e,f] * z[b,i,f]
// One block per j: G[j] (64 KiB) read ONCE (vs 32x before); all 32 batches
// computed per block with z staged in 16 KiB LDS tiles. Thread (e = t&15,
// bh = t>>4) accumulates b = bh and bh+16.
__global__ void k_stage2(const float* __restrict__ G, const float* __restrict__ z,
                         float* __restrict__ w) {
    const int j = blockIdx.x;
    const int t = threadIdx.x;
    const int e  = t & 15;
    const int bh = t >> 4;

    __shared__ float zs[32][128];   // [b][it*16+f] for current i-tile of 8
    const float* Gj = G + (size_t)j * FEAT * EIG * EIG;
    float acc0 = 0.f, acc1 = 0.f;

    for (int i0 = 0; i0 < FEAT; i0 += 8) {
        if (i0) __syncthreads();
        // stage z[b][i0..i0+7][:] : 1024 float4s, 4 per thread
#pragma unroll
        for (int r = 0; r < 4; r++) {
            const int g = t + 256 * r;
            const int bb = g >> 5, rem = g & 31;
            ((float4*)&zs[bb][0])[rem] =
                ((const float4*)z)[(size_t)bb * 256 + i0 * 4 + rem];
        }
        __syncthreads();

#pragma unroll 2
        for (int it = 0; it < 8; it++) {
            const int i = i0 + it;
            const float4* gp = (const float4*)(Gj + ((size_t)i * EIG + e) * EIG);
            const float4 g0 = gp[0], g1 = gp[1], g2 = gp[2], g3 = gp[3];
            const float4* zA = (const float4*)&zs[bh][it * 16];
            const float4* zB = (const float4*)&zs[bh + 16][it * 16];
            const float4 a0 = zA[0], a1 = zA[1], a2 = zA[2], a3 = zA[3];
            const float4 b0 = zB[0], b1 = zB[1], b2 = zB[2], b3 = zB[3];
            acc0 += g0.x*a0.x + g0.y*a0.y + g0.z*a0.z + g0.w*a0.w
                  + g1.x*a1.x + g1.y*a1.y + g1.z*a1.z + g1.w*a1.w
                  + g2.x*a2.x + g2.y*a2.y + g2.z*a2.z + g2.w*a2.w
                  + g3.x*a3.x + g3.y*a3.y + g3.z*a3.z + g3.w*a3.w;
            acc1 += g0.x*b0.x + g0.y*b0.y + g0.z*b0.z + g0.w*b0.w
                  + g1.x*b1.x + g1.y*b1.y + g1.z*b1.z + g1.w*b1.w
                  + g2.x*b2.x + g2.y*b2.y + g2.z*b2.z + g2.w*b2.w
                  + g3.x*b3.x + g3.y*b3.y + g3.z*b3.z + g3.w*b3.w;
        }
    }

    w[((size_t)bh * OUT + j) * EIG + e]        = acc0;
    w[((size_t)(bh+16) * OUT + j) * EIG + e]   = acc1;
}

// out[b,n,j] = sum_e V[n,e] * w[b,j,e]
// 128-thread blocks (8/CU, no VGPR cap pressure). Thread owns 4 j's
// (W[4][4] float4 in regs), float4 stores; wave-inst = 1 KiB contiguous.
#define DOT16(u) (v0.x*W[u][0].x + v0.y*W[u][0].y + v0.z*W[u][0].z + v0.w*W[u][0].w \
                + v1.x*W[u][1].x + v1.y*W[u][1].y + v1.z*W[u][1].z + v1.w*W[u][1].w \
                + v2.x*W[u][2].x + v2.y*W[u][2].y + v2.z*W[u][2].z + v2.w*W[u][2].w \
                + v3.x*W[u][3].x + v3.y*W[u][3].y + v3.z*W[u][3].z + v3.w*W[u][3].w)

#define CH3 64   // 64 chunks x 320 nodes

__global__ __launch_bounds__(128)
void k_stage3(const float* __restrict__ V, const float* __restrict__ w,
              float* __restrict__ out) {
    const int c = blockIdx.x;        // 0..63, 320 nodes each
    const int b = blockIdx.y;
    const int t = threadIdx.x;
    const int jg = t & 15;           // j = 4*jg + u
    const int ns = t >> 4;           // node sub 0..7

    const float* wp = w + ((size_t)b * OUT + 4 * jg) * EIG;
    float4 W[4][4];
#pragma unroll
    for (int u = 0; u < 4; u++)
#pragma unroll
        for (int vr = 0; vr < 4; vr++)
            W[u][vr] = *(const float4*)(wp + u * EIG + vr * 4);

    const int nb = c * 320 + ns;
    float* ob = out + (size_t)b * NODES * OUT + 4 * jg;

#pragma unroll 2
    for (int it = 0; it < 40; it++) {
        const int n = nb + it * 8;
        if (n < NODES) {
            const float* vp = V + (size_t)n * EIG;
            const float4 v0 = *(const float4*)(vp);
            const float4 v1 = *(const float4*)(vp + 4);
            const float4 v2 = *(const float4*)(vp + 8);
            const float4 v3 = *(const float4*)(vp + 12);
            float4 o;
            o.x = DOT16(0);
            o.y = DOT16(1);
            o.z = DOT16(2);
            o.w = DOT16(3);
            *(float4*)(ob + (size_t)n * OUT) = o;
        }
    }
}

extern "C" void kernel_launch(void* const* d_in, const int* in_sizes, int n_in,
                              void* d_out, int out_size, void* d_ws, size_t ws_size,
                              hipStream_t stream) {
    const float* x = (const float*)d_in[0];   // [32, 20000, 64]
    const float* V = (const float*)d_in[1];   // [20000, 16]
    const float* G = (const float*)d_in[2];   // [64, 64, 16, 16]
    float* out = (float*)d_out;               // [32, 20000, 64]

    float* z = (float*)d_ws;                          // [32, 64, 16]
    float* w = z + (size_t)BATCH * FEAT * EIG;        // [32, 64, 16]

    const int zn = BATCH * FEAT * EIG;  // 32768
    k_zero<<<(zn + 255) / 256, 256, 0, stream>>>(z, zn);

    k_stage1<<<dim3(CH1, BATCH), 256, 0, stream>>>(x, V, z);
    k_stage2<<<OUT, 256, 0, stream>>>(G, z, w);
    k_stage3<<<dim3(CH3, BATCH), 128, 0, stream>>>(V, w, out);
}

// Round 7
// 323.601 us; speedup vs baseline: 1.2789x; 1.0922x over previous
//
#include <hip/hip_runtime.h>
#include <stdint.h>

#define BATCH 32
#define NODES 20000
#define FEAT  64
#define OUT   64
#define EIG   16

// ---- stage1: 25 chunks x 800 nodes; 10 tiles of 80 rows, DMA double-buffered ----
#define CH1      25
#define S1_NPB   800
#define S1_TILES 10
#define S1_TR    80        // rows per tile

// async 16B global->LDS copy. Per HW: LDS dest = wave-uniform base + lane*16;
// global src is per-lane. Generic->AS casts via uintptr (flat VA == global VA;
// generic LDS ptr low 32 bits == LDS offset, apertures are 4GiB-aligned).
__device__ __forceinline__ void g2l16(const float* g, float* l) {
    __builtin_amdgcn_global_load_lds(
        (const __attribute__((address_space(1))) uint32_t*)(uintptr_t)g,
        (__attribute__((address_space(3))) uint32_t*)(uintptr_t)l,
        16, 0, 0);
}

#define FMA16(ii, xc) \
    acc[ii][0].x += (xc)*v0.x; acc[ii][0].y += (xc)*v0.y; acc[ii][0].z += (xc)*v0.z; acc[ii][0].w += (xc)*v0.w; \
    acc[ii][1].x += (xc)*v1.x; acc[ii][1].y += (xc)*v1.y; acc[ii][1].z += (xc)*v1.z; acc[ii][1].w += (xc)*v1.w; \
    acc[ii][2].x += (xc)*v2.x; acc[ii][2].y += (xc)*v2.y; acc[ii][2].z += (xc)*v2.z; acc[ii][2].w += (xc)*v2.w; \
    acc[ii][3].x += (xc)*v3.x; acc[ii][3].y += (xc)*v3.y; acc[ii][3].z += (xc)*v3.z; acc[ii][3].w += (xc)*v3.w;

// z[b,i,f] = sum_m V[m,f] * x[b,m,i]
// DMA-staged: while computing tile k from LDS, tile k+1 streams in via
// global_load_lds (7 calls/wave, counted vmcnt(7) so prefetch never drains).
// Lane (ms=lane>>4, ig=lane&15): 4 rows/wave-read, conflict-free (2-way) b128.
// Block writes a deterministic 4KB partial zpart[c][b][1024] (no atomics).
__global__ __launch_bounds__(256)
void k_stage1(const float* __restrict__ x, const float* __restrict__ V,
              float* __restrict__ zpart) {
    const int c = blockIdx.x;
    const int b = blockIdx.y;
    const int t = threadIdx.x;
    const int lane = t & 63;
    const int wv   = t >> 6;
    const int ms   = lane >> 4;
    const int ig   = lane & 15;

    __shared__ __align__(16) float xs[2][S1_TR * FEAT];   // 2 x 20 KiB
    __shared__ __align__(16) float vs[2][S1_TR * EIG];    // 2 x 5 KiB

    const float* xg = x + ((size_t)b * NODES + (size_t)c * S1_NPB) * FEAT;
    const float* vg = V + (size_t)c * S1_NPB * EIG;

    // stage tile tt into buffer d: x 20480B (5 calls/wave) + V 5120B
    // (8 calls total, calls 5-7 duplicate call 4 so every wave issues exactly 7)
    auto stage = [&](int tt, int d) {
#pragma unroll
        for (int k = 0; k < 5; k++) {
            const int off = wv * 1280 + k * 256;
            g2l16(xg + (size_t)tt * S1_TR * FEAT + off + lane * 4, &xs[d][off]);
        }
#pragma unroll
        for (int k = 0; k < 2; k++) {
            const int callid = wv + k * 4;
            const int off = (callid > 4 ? 4 : callid) * 256;
            g2l16(vg + (size_t)tt * S1_TR * EIG + off + lane * 4, &vs[d][off]);
        }
    };

    float4 acc[4][4];
#pragma unroll
    for (int ii = 0; ii < 4; ii++)
#pragma unroll
        for (int q = 0; q < 4; q++) acc[ii][q] = make_float4(0.f,0.f,0.f,0.f);

    stage(0, 0);

    for (int tt = 0; tt < S1_TILES; tt++) {
        const int d = tt & 1;
        if (tt < S1_TILES - 1) {
            stage(tt + 1, d ^ 1);
            asm volatile("s_waitcnt vmcnt(7)" ::: "memory");   // tile tt landed
        } else {
            asm volatile("s_waitcnt vmcnt(0)" ::: "memory");
        }
        __builtin_amdgcn_s_barrier();
        __builtin_amdgcn_sched_barrier(0);

        const float* xt = &xs[d][wv * 20 * FEAT];
        const float* vt = &vs[d][wv * 20 * EIG];
#pragma unroll
        for (int itr = 0; itr < 5; itr++) {
            const int r = itr * 4 + ms;
            const float4 xv = *(const float4*)(xt + r * FEAT + ig * 4);
            const float4 v0 = *(const float4*)(vt + r * EIG);
            const float4 v1 = *(const float4*)(vt + r * EIG + 4);
            const float4 v2 = *(const float4*)(vt + r * EIG + 8);
            const float4 v3 = *(const float4*)(vt + r * EIG + 12);
            FMA16(0, xv.x); FMA16(1, xv.y); FMA16(2, xv.z); FMA16(3, xv.w);
        }
        __builtin_amdgcn_sched_barrier(0);   // keep ds_reads on this side
        __builtin_amdgcn_s_barrier();        // all reads of d done before restage
    }

    // reduce over ms groups (lanes l, l^16, l^32, l^48)
#pragma unroll
    for (int ii = 0; ii < 4; ii++)
#pragma unroll
        for (int q = 0; q < 4; q++) {
            acc[ii][q].x += __shfl_xor(acc[ii][q].x, 16); acc[ii][q].x += __shfl_xor(acc[ii][q].x, 32);
            acc[ii][q].y += __shfl_xor(acc[ii][q].y, 16); acc[ii][q].y += __shfl_xor(acc[ii][q].y, 32);
            acc[ii][q].z += __shfl_xor(acc[ii][q].z, 16); acc[ii][q].z += __shfl_xor(acc[ii][q].z, 32);
            acc[ii][q].w += __shfl_xor(acc[ii][q].w, 16); acc[ii][q].w += __shfl_xor(acc[ii][q].w, 32);
        }

    // cross-wave combine (reuse xs as scratch; 16 KiB needed, 40 KiB available)
    float4* zred = (float4*)&xs[0][0];
    __syncthreads();
    if (ms == 0) {
#pragma unroll
        for (int ii = 0; ii < 4; ii++)
#pragma unroll
            for (int q = 0; q < 4; q++)
                zred[wv * 256 + ig * 16 + ii * 4 + q] = acc[ii][q];
    }
    __syncthreads();

    // thread t holds z[b][t*4 .. t*4+3] (layout algebra: i=t>>2, f=(t&3)*4+r)
    float4 s  = zred[t];
    const float4 s1 = zred[256 + t];
    const float4 s2 = zred[512 + t];
    const float4 s3 = zred[768 + t];
    s.x += s1.x + s2.x + s3.x;
    s.y += s1.y + s2.y + s3.y;
    s.z += s1.z + s2.z + s3.z;
    s.w += s1.w + s2.w + s3.w;
    *(float4*)(zpart + ((size_t)c * BATCH + b) * (FEAT * EIG) + t * 4) = s;
}

// z[b] = sum_c zpart[c][b]  (256 float4s per b, one per thread); bx==1 zeroes w
__global__ void k_reduce(const float* __restrict__ zpart, float* __restrict__ z,
                         float* __restrict__ w) {
    const int b = blockIdx.y;
    const int t = threadIdx.x;
    if (blockIdx.x == 1) {
        ((float4*)w)[b * 256 + t] = make_float4(0.f, 0.f, 0.f, 0.f);
        return;
    }
    float4 s = make_float4(0.f, 0.f, 0.f, 0.f);
#pragma unroll
    for (int c = 0; c < CH1; c++) {
        const float4 v = ((const float4*)zpart)[((size_t)c * BATCH + b) * 256 + t];
        s.x += v.x; s.y += v.y; s.z += v.z; s.w += v.w;
    }
    ((float4*)z)[(size_t)b * 256 + t] = s;
}

// w[b,j,e] += sum_{i in 8-slice} G[j,i,e,f] * z[b,i,f]
// grid (64 j, 8 iq) = 512 blocks (2/CU): short G chains, good latency overlap.
__global__ void k_stage2(const float* __restrict__ G, const float* __restrict__ z,
                         float* __restrict__ w) {
    const int j  = blockIdx.x;
    const int iq = blockIdx.y;
    const int t = threadIdx.x;
    const int e  = t & 15;
    const int bh = t >> 4;

    __shared__ float zs[32][128];   // z[b][i-slice][f], 16 KiB
#pragma unroll
    for (int r = 0; r < 4; r++) {
        const int g = t + 256 * r;
        const int bb = g >> 5, off = g & 31;
        ((float4*)&zs[bb][0])[off] =
            ((const float4*)z)[(size_t)bb * 256 + iq * 32 + off];
    }
    __syncthreads();

    const float* Gj = G + (size_t)j * FEAT * EIG * EIG;
    float acc0 = 0.f, acc1 = 0.f;

#pragma unroll 2
    for (int it = 0; it < 8; it++) {
        const int i = iq * 8 + it;
        const float4* gp = (const float4*)(Gj + ((size_t)i * EIG + e) * EIG);
        const float4 g0 = gp[0], g1 = gp[1], g2 = gp[2], g3 = gp[3];
        const float4* zA = (const float4*)&zs[bh][it * 16];
        const float4* zB = (const float4*)&zs[bh + 16][it * 16];
        const float4 a0 = zA[0], a1 = zA[1], a2 = zA[2], a3 = zA[3];
        const float4 b0 = zB[0], b1 = zB[1], b2 = zB[2], b3 = zB[3];
        acc0 += g0.x*a0.x + g0.y*a0.y + g0.z*a0.z + g0.w*a0.w
              + g1.x*a1.x + g1.y*a1.y + g1.z*a1.z + g1.w*a1.w
              + g2.x*a2.x + g2.y*a2.y + g2.z*a2.z + g2.w*a2.w
              + g3.x*a3.x + g3.y*a3.y + g3.z*a3.z + g3.w*a3.w;
        acc1 += g0.x*b0.x + g0.y*b0.y + g0.z*b0.z + g0.w*b0.w
              + g1.x*b1.x + g1.y*b1.y + g1.z*b1.z + g1.w*b1.w
              + g2.x*b2.x + g2.y*b2.y + g2.z*b2.z + g2.w*b2.w
              + g3.x*b3.x + g3.y*b3.y + g3.z*b3.z + g3.w*b3.w;
    }

    atomicAdd(&w[((size_t)bh * OUT + j) * EIG + e], acc0);
    atomicAdd(&w[((size_t)(bh + 16) * OUT + j) * EIG + e], acc1);
}

// out[b,n,j] = sum_e V[n,e] * w[b,j,e]
// Thread owns 4 j's (W in 64 regs); V rows double-buffered in regs so the
// load latency hides under FMAs+stores; float4 stores (1 KiB/wave-inst).
#define DOT16(u) (v0.x*W[u][0].x + v0.y*W[u][0].y + v0.z*W[u][0].z + v0.w*W[u][0].w \
                + v1.x*W[u][1].x + v1.y*W[u][1].y + v1.z*W[u][1].z + v1.w*W[u][1].w \
                + v2.x*W[u][2].x + v2.y*W[u][2].y + v2.z*W[u][2].z + v2.w*W[u][2].w \
                + v3.x*W[u][3].x + v3.y*W[u][3].y + v3.z*W[u][3].z + v3.w*W[u][3].w)

#define CH3 64   // 64 chunks x 320 nodes

__global__ __launch_bounds__(128, 4)
void k_stage3(const float* __restrict__ V, const float* __restrict__ w,
              float* __restrict__ out) {
    const int c = blockIdx.x;
    const int b = blockIdx.y;
    const int t = threadIdx.x;
    const int jg = t & 15;
    const int ns = t >> 4;           // 0..7

    const float* wp = w + ((size_t)b * OUT + 4 * jg) * EIG;
    float4 W[4][4];
#pragma unroll
    for (int u = 0; u < 4; u++)
#pragma unroll
        for (int vr = 0; vr < 4; vr++)
            W[u][vr] = *(const float4*)(wp + u * EIG + vr * 4);

    const int nb = c * 320 + ns;
    float* ob = out + (size_t)b * NODES * OUT + 4 * jg;

    int n = nb;
    bool val = (n < NODES);
    float4 v0 = make_float4(0,0,0,0), v1 = v0, v2 = v0, v3 = v0;
    if (val) {
        const float* vp = V + (size_t)n * EIG;
        v0 = *(const float4*)(vp);      v1 = *(const float4*)(vp + 4);
        v2 = *(const float4*)(vp + 8);  v3 = *(const float4*)(vp + 12);
    }

    for (int it = 0; it < 40; it++) {
        const int n2 = nb + (it + 1) * 8;
        const bool val2 = (it < 39) && (n2 < NODES);
        float4 u0 = make_float4(0,0,0,0), u1 = u0, u2 = u0, u3 = u0;
        if (val2) {   // prefetch next V row while computing current
            const float* vp = V + (size_t)n2 * EIG;
            u0 = *(const float4*)(vp);      u1 = *(const float4*)(vp + 4);
            u2 = *(const float4*)(vp + 8);  u3 = *(const float4*)(vp + 12);
        }
        if (val) {
            float4 o;
            o.x = DOT16(0); o.y = DOT16(1); o.z = DOT16(2); o.w = DOT16(3);
            *(float4*)(ob + (size_t)n * OUT) = o;
        }
        v0 = u0; v1 = u1; v2 = u2; v3 = u3;
        n = n2; val = val2;
    }
}

extern "C" void kernel_launch(void* const* d_in, const int* in_sizes, int n_in,
                              void* d_out, int out_size, void* d_ws, size_t ws_size,
                              hipStream_t stream) {
    const float* x = (const float*)d_in[0];   // [32, 20000, 64]
    const float* V = (const float*)d_in[1];   // [20000, 16]
    const float* G = (const float*)d_in[2];   // [64, 64, 16, 16]
    float* out = (float*)d_out;               // [32, 20000, 64]

    float* z     = (float*)d_ws;                               // 32K floats
    float* w     = z + (size_t)BATCH * FEAT * EIG;             // 32K floats
    float* zpart = w + (size_t)BATCH * OUT * EIG;              // 25*32*1024 floats

    k_stage1<<<dim3(CH1, BATCH), 256, 0, stream>>>(x, V, zpart);
    k_reduce<<<dim3(2, BATCH), 256, 0, stream>>>(zpart, z, w);
    k_stage2<<<dim3(OUT, 8), 256, 0, stream>>>(G, z, w);
    k_stage3<<<dim3(CH3, BATCH), 128, 0, stream>>>(V, w, out);
}

// Round 12
// 318.704 us; speedup vs baseline: 1.2985x; 1.0154x over previous
//
#include <hip/hip_runtime.h>
#include <stdint.h>

#define BATCH 32
#define NODES 20000
#define FEAT  64
#define OUT   64
#define EIG   16

// ---- stage1: 25 chunks x 800 nodes; 10 tiles of 80 rows; per-wave private
// double-buffers, BARRIER-FREE counted-vmcnt pipeline (wave stages only its
// own 20-row quarter; vmcnt is per-wave; no cross-wave LDS sharing) ----
#define CH1      25
#define S1_NPB   800
#define S1_TILES 10

__device__ __forceinline__ void g2l16(const float* g, float* l) {
    __builtin_amdgcn_global_load_lds(
        (const __attribute__((address_space(1))) uint32_t*)(uintptr_t)g,
        (__attribute__((address_space(3))) uint32_t*)(uintptr_t)l,
        16, 0, 0);
}
__device__ __forceinline__ void g2l4(const float* g, float* l) {
    __builtin_amdgcn_global_load_lds(
        (const __attribute__((address_space(1))) uint32_t*)(uintptr_t)g,
        (__attribute__((address_space(3))) uint32_t*)(uintptr_t)l,
        4, 0, 0);
}

#define FMA16(ii, xc) \
    acc[ii][0].x += (xc)*v0.x; acc[ii][0].y += (xc)*v0.y; acc[ii][0].z += (xc)*v0.z; acc[ii][0].w += (xc)*v0.w; \
    acc[ii][1].x += (xc)*v1.x; acc[ii][1].y += (xc)*v1.y; acc[ii][1].z += (xc)*v1.z; acc[ii][1].w += (xc)*v1.w; \
    acc[ii][2].x += (xc)*v2.x; acc[ii][2].y += (xc)*v2.y; acc[ii][2].z += (xc)*v2.z; acc[ii][2].w += (xc)*v2.w; \
    acc[ii][3].x += (xc)*v3.x; acc[ii][3].y += (xc)*v3.y; acc[ii][3].z += (xc)*v3.z; acc[ii][3].w += (xc)*v3.w;

// z[b,i,f] = sum_m V[m,f] * x[b,m,i]
// Wave wv owns rows [wv*20, wv*20+20) of each 80-row tile. Per tile per wave:
// 7 DMA calls (5x16B x = 5 KiB, 1x16B + 1x4B V = 1.25 KiB) -> exact ledger:
// after staging tile t+1, vmcnt(7) == "tile t landed". No s_barrier anywhere
// in the main loop; waves self-pace. Block writes deterministic partial.
__global__ __launch_bounds__(256)
void k_stage1(const float* __restrict__ x, const float* __restrict__ V,
              float* __restrict__ zpart) {
    const int c = blockIdx.x;
    const int b = blockIdx.y;
    const int t = threadIdx.x;
    const int lane = t & 63;
    const int wv   = t >> 6;
    const int ms   = lane >> 4;
    const int ig   = lane & 15;

    __shared__ __align__(16) float xsl[2][4][20 * FEAT];  // 40 KiB (per-wave 5 KiB)
    __shared__ __align__(16) float vsl[2][4][20 * EIG];   // 10 KiB (per-wave 1.25 KiB)

    const float* xw = x + ((size_t)b * NODES + (size_t)c * S1_NPB + wv * 20) * FEAT;
    const float* vw = V + ((size_t)c * S1_NPB + wv * 20) * EIG;

    auto stage = [&](int tt, int d) {
        const float* xsrc = xw + (size_t)tt * 80 * FEAT;
        const float* vsrc = vw + (size_t)tt * 80 * EIG;
#pragma unroll
        for (int k = 0; k < 5; k++)
            g2l16(xsrc + k * 256 + lane * 4, &xsl[d][wv][k * 256]);
        g2l16(vsrc + lane * 4, &vsl[d][wv][0]);
        g2l4 (vsrc + 256 + lane, &vsl[d][wv][256]);
    };

    float4 acc[4][4];
#pragma unroll
    for (int ii = 0; ii < 4; ii++)
#pragma unroll
        for (int q = 0; q < 4; q++) acc[ii][q] = make_float4(0.f,0.f,0.f,0.f);

    stage(0, 0);

    for (int tt = 0; tt < S1_TILES; tt++) {
        const int d = tt & 1;
        if (tt < S1_TILES - 1) {
            stage(tt + 1, d ^ 1);
            asm volatile("s_waitcnt vmcnt(7)" ::: "memory");   // own tile tt landed
        } else {
            asm volatile("s_waitcnt vmcnt(0)" ::: "memory");
        }
        __builtin_amdgcn_sched_barrier(0);

        const float* xt = &xsl[d][wv][0];
        const float* vt = &vsl[d][wv][0];
#pragma unroll
        for (int itr = 0; itr < 5; itr++) {
            const int r = itr * 4 + ms;
            const float4 xv = *(const float4*)(xt + r * FEAT + ig * 4);
            const float4 v0 = *(const float4*)(vt + r * EIG);
            const float4 v1 = *(const float4*)(vt + r * EIG + 4);
            const float4 v2 = *(const float4*)(vt + r * EIG + 8);
            const float4 v3 = *(const float4*)(vt + r * EIG + 12);
            FMA16(0, xv.x); FMA16(1, xv.y); FMA16(2, xv.z); FMA16(3, xv.w);
        }
    }

    // reduce over ms groups (lanes l, l^16, l^32, l^48)
#pragma unroll
    for (int ii = 0; ii < 4; ii++)
#pragma unroll
        for (int q = 0; q < 4; q++) {
            acc[ii][q].x += __shfl_xor(acc[ii][q].x, 16); acc[ii][q].x += __shfl_xor(acc[ii][q].x, 32);
            acc[ii][q].y += __shfl_xor(acc[ii][q].y, 16); acc[ii][q].y += __shfl_xor(acc[ii][q].y, 32);
            acc[ii][q].z += __shfl_xor(acc[ii][q].z, 16); acc[ii][q].z += __shfl_xor(acc[ii][q].z, 32);
            acc[ii][q].w += __shfl_xor(acc[ii][q].w, 16); acc[ii][q].w += __shfl_xor(acc[ii][q].w, 32);
        }

    // cross-wave combine (reuse xsl as scratch AFTER the sync; 16 KiB of 40)
    float4* zred = (float4*)&xsl[0][0][0];
    __syncthreads();
    if (ms == 0) {
#pragma unroll
        for (int ii = 0; ii < 4; ii++)
#pragma unroll
            for (int q = 0; q < 4; q++)
                zred[wv * 256 + ig * 16 + ii * 4 + q] = acc[ii][q];
    }
    __syncthreads();

    // thread t holds z[b][t*4 .. t*4+3] (identity layout, verified R7)
    float4 s  = zred[t];
    const float4 s1 = zred[256 + t];
    const float4 s2 = zred[512 + t];
    const float4 s3 = zred[768 + t];
    s.x += s1.x + s2.x + s3.x;
    s.y += s1.y + s2.y + s3.y;
    s.z += s1.z + s2.z + s3.z;
    s.w += s1.w + s2.w + s3.w;
    *(float4*)(zpart + ((size_t)c * BATCH + b) * (FEAT * EIG) + t * 4) = s;
}

// z[b] = sum_c zpart[c][b]  (256 float4s per b, one per thread); bx==1 zeroes w
__global__ void k_reduce(const float* __restrict__ zpart, float* __restrict__ z,
                         float* __restrict__ w) {
    const int b = blockIdx.y;
    const int t = threadIdx.x;
    if (blockIdx.x == 1) {
        ((float4*)w)[b * 256 + t] = make_float4(0.f, 0.f, 0.f, 0.f);
        return;
    }
    float4 s = make_float4(0.f, 0.f, 0.f, 0.f);
#pragma unroll
    for (int c = 0; c < CH1; c++) {
        const float4 v = ((const float4*)zpart)[((size_t)c * BATCH + b) * 256 + t];
        s.x += v.x; s.y += v.y; s.z += v.z; s.w += v.w;
    }
    ((float4*)z)[(size_t)b * 256 + t] = s;
}

// w[b,j,e] += sum_{i in 8-slice} G[j,i,e,f] * z[b,i,f]   (512 blocks, atomics)
__global__ void k_stage2(const float* __restrict__ G, const float* __restrict__ z,
                         float* __restrict__ w) {
    const int j  = blockIdx.x;
    const int iq = blockIdx.y;
    const int t = threadIdx.x;
    const int e  = t & 15;
    const int bh = t >> 4;

    __shared__ float zs[32][128];
#pragma unroll
    for (int r = 0; r < 4; r++) {
        const int g = t + 256 * r;
        const int bb = g >> 5, off = g & 31;
        ((float4*)&zs[bb][0])[off] =
            ((const float4*)z)[(size_t)bb * 256 + iq * 32 + off];
    }
    __syncthreads();

    const float* Gj = G + (size_t)j * FEAT * EIG * EIG;
    float acc0 = 0.f, acc1 = 0.f;

#pragma unroll 2
    for (int it = 0; it < 8; it++) {
        const int i = iq * 8 + it;
        const float4* gp = (const float4*)(Gj + ((size_t)i * EIG + e) * EIG);
        const float4 g0 = gp[0], g1 = gp[1], g2 = gp[2], g3 = gp[3];
        const float4* zA = (const float4*)&zs[bh][it * 16];
        const float4* zB = (const float4*)&zs[bh + 16][it * 16];
        const float4 a0 = zA[0], a1 = zA[1], a2 = zA[2], a3 = zA[3];
        const float4 b0 = zB[0], b1 = zB[1], b2 = zB[2], b3 = zB[3];
        acc0 += g0.x*a0.x + g0.y*a0.y + g0.z*a0.z + g0.w*a0.w
              + g1.x*a1.x + g1.y*a1.y + g1.z*a1.z + g1.w*a1.w
              + g2.x*a2.x + g2.y*a2.y + g2.z*a2.z + g2.w*a2.w
              + g3.x*a3.x + g3.y*a3.y + g3.z*a3.z + g3.w*a3.w;
        acc1 += g0.x*b0.x + g0.y*b0.y + g0.z*b0.z + g0.w*b0.w
              + g1.x*b1.x + g1.y*b1.y + g1.z*b1.z + g1.w*b1.w
              + g2.x*b2.x + g2.y*b2.y + g2.z*b2.z + g2.w*b2.w
              + g3.x*b3.x + g3.y*b3.y + g3.z*b3.z + g3.w*b3.w;
    }

    atomicAdd(&w[((size_t)bh * OUT + j) * EIG + e], acc0);
    atomicAdd(&w[((size_t)(bh + 16) * OUT + j) * EIG + e], acc1);
}

// out[b,n,j] = sum_e V[n,e] * w[b,j,e]
// 256-thr blocks, 1024 total = 4/CU one round. XCD-bijective c-swizzle so each
// XCD writes a contiguous 640 KB per b. Nontemporal float4 stores (out is
// never re-read; don't pollute L2/L3 where x must stay resident).
#define DOT16(u) (v0.x*W[u][0].x + v0.y*W[u][0].y + v0.z*W[u][0].z + v0.w*W[u][0].w \
                + v1.x*W[u][1].x + v1.y*W[u][1].y + v1.z*W[u][1].z + v1.w*W[u][1].w \
                + v2.x*W[u][2].x + v2.y*W[u][2].y + v2.z*W[u][2].z + v2.w*W[u][2].w \
                + v3.x*W[u][3].x + v3.y*W[u][3].y + v3.z*W[u][3].z + v3.w*W[u][3].w)

#define CH3 64   // 64 chunks x 320 nodes

typedef float f32x4 __attribute__((ext_vector_type(4)));

__global__ __launch_bounds__(256)
void k_stage3(const float* __restrict__ V, const float* __restrict__ w,
              float* __restrict__ out) {
    const int craw = blockIdx.x;
    const int c = (craw & 7) * 8 + (craw >> 3);   // bijective: 64 = 8 x 8
    const int b = blockIdx.y;
    const int t = threadIdx.x;
    const int jg = t & 15;
    const int ns = t >> 4;           // 0..15

    const float* wp = w + ((size_t)b * OUT + 4 * jg) * EIG;
    float4 W[4][4];
#pragma unroll
    for (int u = 0; u < 4; u++)
#pragma unroll
        for (int vr = 0; vr < 4; vr++)
            W[u][vr] = *(const float4*)(wp + u * EIG + vr * 4);

    const int nb = c * 320 + ns;
    float* ob = out + (size_t)b * NODES * OUT + 4 * jg;

    int n = nb;
    bool val = (n < NODES);
    float4 v0 = make_float4(0,0,0,0), v1 = v0, v2 = v0, v3 = v0;
    if (val) {
        const float* vp = V + (size_t)n * EIG;
        v0 = *(const float4*)(vp);      v1 = *(const float4*)(vp + 4);
        v2 = *(const float4*)(vp + 8);  v3 = *(const float4*)(vp + 12);
    }

    for (int it = 0; it < 20; it++) {
        const int n2 = nb + (it + 1) * 16;
        const bool val2 = (it < 19) && (n2 < NODES);
        float4 u0 = make_float4(0,0,0,0), u1 = u0, u2 = u0, u3 = u0;
        if (val2) {   // prefetch next V row while computing current
            const float* vp = V + (size_t)n2 * EIG;
            u0 = *(const float4*)(vp);      u1 = *(const float4*)(vp + 4);
            u2 = *(const float4*)(vp + 8);  u3 = *(const float4*)(vp + 12);
        }
        if (val) {
            f32x4 o;
            o[0] = DOT16(0); o[1] = DOT16(1); o[2] = DOT16(2); o[3] = DOT16(3);
            __builtin_nontemporal_store(o, (f32x4*)(ob + (size_t)n * OUT));
        }
        v0 = u0; v1 = u1; v2 = u2; v3 = u3;
        n = n2; val = val2;
    }
}

extern "C" void kernel_launch(void* const* d_in, const int* in_sizes, int n_in,
                              void* d_out, int out_size, void* d_ws, size_t ws_size,
                              hipStream_t stream) {
    const float* x = (const float*)d_in[0];   // [32, 20000, 64]
    const float* V = (const float*)d_in[1];   // [20000, 16]
    const float* G = (const float*)d_in[2];   // [64, 64, 16, 16]
    float* out = (float*)d_out;               // [32, 20000, 64]

    float* z     = (float*)d_ws;                               // 32K floats
    float* w     = z + (size_t)BATCH * FEAT * EIG;             // 32K floats
    float* zpart = w + (size_t)BATCH * OUT * EIG;              // 25*32*1024 floats

    k_stage1<<<dim3(CH1, BATCH), 256, 0, stream>>>(x, V, zpart);
    k_reduce<<<dim3(2, BATCH), 256, 0, stream>>>(zpart, z, w);
    k_stage2<<<dim3(OUT, 8), 256, 0, stream>>>(G, z, w);
    k_stage3<<<dim3(CH3, BATCH), 256, 0, stream>>>(V, w, out);
}